// Round 4
// baseline (536.304 us; speedup 1.0000x reference)
//
#include <hip/hip_runtime.h>
#include <hip/hip_bf16.h>

// SNN: B=2048, NI=1024, NH=2048, NO=10, T=128, BETA=0.95, THR=1.0
// d_in: x[2048,1024], w1[2048,1024], b1[2048], w2[10,2048], b2[10]  (all f32)
// d_out: spk2_rec[128,2048,10] ++ mem2_rec[128,2048,10]  (f32)
// d_ws: cur1[2048,2048] f32 = 16 MB

#define B_   2048
#define NI_  1024
#define NH_  2048
#define NO_  10
#define T_   128

// ---------------- Kernel 1: cur1 = x @ w1^T + b1 (fp32, LDS-tiled) ----------
#define BK 32

__global__ __launch_bounds__(256) void gemm_cur1(
    const float* __restrict__ x, const float* __restrict__ w1,
    const float* __restrict__ b1, float* __restrict__ cur1) {
  // C[b,h] = sum_k x[b,k] * w1[h,k] + b1[h]
  __shared__ __align__(16) float At[BK][68];  // +4 pad: bank spread, 16B rows
  __shared__ __align__(16) float Bt[BK][68];
  const int tid = threadIdx.x;
  const int brow = blockIdx.y * 64;
  const int bcol = blockIdx.x * 64;
  const int tr = tid >> 4;     // 0..15 -> 4 rows each
  const int tc = tid & 15;     // 0..15 -> 4 cols each

  float acc[4][4] = {};

  for (int kt = 0; kt < NI_; kt += BK) {
#pragma unroll
    for (int p = 0; p < 2; ++p) {
      const int f = tid + p * 256;      // 0..511 float4 slots
      const int row = f >> 3;           // 0..63
      const int kq = f & 7;             // float4 within the 32-wide K tile
      const float4 av = *reinterpret_cast<const float4*>(
          &x[(size_t)(brow + row) * NI_ + kt + kq * 4]);
      const float4 bv = *reinterpret_cast<const float4*>(
          &w1[(size_t)(bcol + row) * NI_ + kt + kq * 4]);
      At[kq * 4 + 0][row] = av.x; At[kq * 4 + 1][row] = av.y;
      At[kq * 4 + 2][row] = av.z; At[kq * 4 + 3][row] = av.w;
      Bt[kq * 4 + 0][row] = bv.x; Bt[kq * 4 + 1][row] = bv.y;
      Bt[kq * 4 + 2][row] = bv.z; Bt[kq * 4 + 3][row] = bv.w;
    }
    __syncthreads();
#pragma unroll 8
    for (int kk = 0; kk < BK; ++kk) {
      const float4 a4 = *reinterpret_cast<const float4*>(&At[kk][tr * 4]);
      const float4 b4 = *reinterpret_cast<const float4*>(&Bt[kk][tc * 4]);
      const float av[4] = {a4.x, a4.y, a4.z, a4.w};
      const float bv[4] = {b4.x, b4.y, b4.z, b4.w};
#pragma unroll
      for (int i = 0; i < 4; ++i)
#pragma unroll
        for (int j = 0; j < 4; ++j)
          acc[i][j] = fmaf(av[i], bv[j], acc[i][j]);
    }
    __syncthreads();
  }

#pragma unroll
  for (int i = 0; i < 4; ++i) {
    const int bb = brow + tr * 4 + i;
#pragma unroll
    for (int j = 0; j < 4; ++j) {
      const int hh = bcol + tc * 4 + j;
      cur1[(size_t)bb * NH_ + hh] = acc[i][j] + b1[hh];
    }
  }
}

// ---------------- DPP wave-64 sum (VALU pipe; result valid in lane 63) ------
template <int CTRL>
__device__ __forceinline__ float dpp_add(float x) {
  const int s = __builtin_amdgcn_update_dpp(0, __float_as_int(x), CTRL, 0xf, 0xf, false);
  return x + __int_as_float(s);
}
__device__ __forceinline__ float wave_sum64(float x) {
  x = dpp_add<0x111>(x);  // row_shr:1
  x = dpp_add<0x112>(x);  // row_shr:2
  x = dpp_add<0x114>(x);  // row_shr:4
  x = dpp_add<0x118>(x);  // row_shr:8   -> lane 16r+15 = sum of row r
  x = dpp_add<0x142>(x);  // row_bcast:15
  x = dpp_add<0x143>(x);  // row_bcast:31 -> lane 63 = full sum
  return x;
}

// ---------------- Kernel 2: fused 128-step LIF loop, one block per batch ----
__global__ __launch_bounds__(256) void snn_loop(
    const float* __restrict__ cur1, const float* __restrict__ w2,
    const float* __restrict__ b2, float* __restrict__ spk2_rec,
    float* __restrict__ mem2_rec) {
  const int b = blockIdx.x;        // batch row
  const int tid = threadIdx.x;     // 0..255
  const int lane = tid & 63;
  const int wv = tid >> 6;         // wave 0..3

  __shared__ float partsLDS[2][4][NO_];  // [step parity][wave][o]

  // Register state: 8 strided h's per thread (h = tid + k*256)
  float mem1[8], c1[8], spk[8];
  float w2r[NO_][8];
#pragma unroll
  for (int k = 0; k < 8; ++k) {
    const int h = tid + k * 256;
    c1[k] = cur1[(size_t)b * NH_ + h];
    mem1[k] = 0.0f;
    spk[k] = 0.0f;
#pragma unroll
    for (int o = 0; o < NO_; ++o) w2r[o][k] = w2[(size_t)o * NH_ + h];
  }

  // mem2 state lives in threads 0..9 (one output each)
  float mem2 = 0.0f, spk2 = 0.0f, b2v = 0.0f;
  if (tid < NO_) b2v = b2[tid];
  float* srec = spk2_rec + (size_t)b * NO_ + tid;
  float* mrec = mem2_rec + (size_t)b * NO_ + tid;

  for (int t = 0; t < T_; ++t) {
    float part[NO_] = {0, 0, 0, 0, 0, 0, 0, 0, 0, 0};
#pragma unroll
    for (int k = 0; k < 8; ++k) {
      // snntorch Leaky, reset-by-subtraction (reset uses PREVIOUS mem > THR,
      // which equals the previous step's spike). Uncontracted ops to match
      // the numpy reference's elementwise rounding.
      float m = __fmul_rn(0.95f, mem1[k]);
      m = __fadd_rn(m, c1[k]);
      m = __fsub_rn(m, spk[k]);
      mem1[k] = m;
      const float s = (m > 1.0f) ? 1.0f : 0.0f;
      spk[k] = s;
#pragma unroll
      for (int o = 0; o < NO_; ++o) part[o] = fmaf(s, w2r[o][k], part[o]);
    }
    // wave-level reduction on the VALU pipe
#pragma unroll
    for (int o = 0; o < NO_; ++o) part[o] = wave_sum64(part[o]);
    if (lane == 63) {
#pragma unroll
      for (int o = 0; o < NO_; ++o) partsLDS[t & 1][wv][o] = part[o];
    }
    __syncthreads();
    if (tid < NO_) {
      const float cur2 = ((partsLDS[t & 1][0][tid] + partsLDS[t & 1][1][tid]) +
                          (partsLDS[t & 1][2][tid] + partsLDS[t & 1][3][tid])) +
                         b2v;
      float m = __fmul_rn(0.95f, mem2);
      m = __fadd_rn(m, cur2);
      m = __fsub_rn(m, spk2);
      mem2 = m;
      spk2 = (m > 1.0f) ? 1.0f : 0.0f;
      srec[(size_t)t * (B_ * NO_)] = spk2;
      mrec[(size_t)t * (B_ * NO_)] = m;
    }
    // double-buffered partsLDS parity => one barrier per step is sufficient
  }
}

// ---------------------------------------------------------------------------
extern "C" void kernel_launch(void* const* d_in, const int* in_sizes, int n_in,
                              void* d_out, int out_size, void* d_ws, size_t ws_size,
                              hipStream_t stream) {
  const float* x  = (const float*)d_in[0];
  const float* w1 = (const float*)d_in[1];
  const float* b1 = (const float*)d_in[2];
  const float* w2 = (const float*)d_in[3];
  const float* b2 = (const float*)d_in[4];
  float* out = (float*)d_out;
  float* cur1 = (float*)d_ws;  // 2048*2048*4 = 16 MB scratch

  float* spk2_rec = out;
  float* mem2_rec = out + (size_t)T_ * B_ * NO_;

  dim3 g1(NH_ / 64, B_ / 64);
  gemm_cur1<<<g1, 256, 0, stream>>>(x, w1, b1, cur1);
  snn_loop<<<B_, 256, 0, stream>>>(cur1, w2, b2, spk2_rec, mem2_rec);
}

// Round 6
// 279.523 us; speedup vs baseline: 1.9186x; 1.9186x over previous
//
#include <hip/hip_runtime.h>
#include <hip/hip_bf16.h>

// SNN: B=2048, NI=1024, NH=2048, NO=10, T=128, BETA=0.95, THR=1.0
// d_in: x[2048,1024], w1[2048,1024], b1[2048], w2[10,2048], b2[10]  (all f32)
// d_out: spk2_rec[128,2048,10] ++ mem2_rec[128,2048,10]  (f32)
// d_ws: cur1[2048,2048] f32 = 16 MB

#define B_   2048
#define NI_  1024
#define NH_  2048
#define NO_  10
#define T_   128
#define GB_  8          // batches per block
#define NBLK (B_ / GB_) // 256 blocks = 1 per CU

typedef __attribute__((ext_vector_type(8))) short short8;
typedef __attribute__((ext_vector_type(4))) float f32x4;
typedef __attribute__((ext_vector_type(4))) unsigned int u32x4;

// A-tile in LDS: 64 MFMA instances (kb = 0..63), each 64 lanes x 16B,
// padded to 1040B so lane-strided b128 access spreads across banks.
#define INST_STRIDE 1040
#define A_BYTES     (64 * INST_STRIDE)          // 66560
#define COMB_OFF    A_BYTES                     // 8 waves x 1 KB
#define SMEM_BYTES  (A_BYTES + 8 * 1024)        // 74752

// ---------------- Kernel 1: cur1 = x @ w1^T + b1 (fp32, LDS-tiled) ----------
#define BK 32

__global__ __launch_bounds__(256) void gemm_cur1(
    const float* __restrict__ x, const float* __restrict__ w1,
    const float* __restrict__ b1, float* __restrict__ cur1) {
  __shared__ __align__(16) float At[BK][68];
  __shared__ __align__(16) float Bt[BK][68];
  const int tid = threadIdx.x;
  const int brow = blockIdx.y * 64;
  const int bcol = blockIdx.x * 64;
  const int tr = tid >> 4;
  const int tc = tid & 15;

  float acc[4][4] = {};

  for (int kt = 0; kt < NI_; kt += BK) {
#pragma unroll
    for (int p = 0; p < 2; ++p) {
      const int f = tid + p * 256;
      const int row = f >> 3;
      const int kq = f & 7;
      const float4 av = *reinterpret_cast<const float4*>(
          &x[(size_t)(brow + row) * NI_ + kt + kq * 4]);
      const float4 bv = *reinterpret_cast<const float4*>(
          &w1[(size_t)(bcol + row) * NI_ + kt + kq * 4]);
      At[kq * 4 + 0][row] = av.x; At[kq * 4 + 1][row] = av.y;
      At[kq * 4 + 2][row] = av.z; At[kq * 4 + 3][row] = av.w;
      Bt[kq * 4 + 0][row] = bv.x; Bt[kq * 4 + 1][row] = bv.y;
      Bt[kq * 4 + 2][row] = bv.z; Bt[kq * 4 + 3][row] = bv.w;
    }
    __syncthreads();
#pragma unroll 8
    for (int kk = 0; kk < BK; ++kk) {
      const float4 a4 = *reinterpret_cast<const float4*>(&At[kk][tr * 4]);
      const float4 b4 = *reinterpret_cast<const float4*>(&Bt[kk][tc * 4]);
      const float av[4] = {a4.x, a4.y, a4.z, a4.w};
      const float bv[4] = {b4.x, b4.y, b4.z, b4.w};
#pragma unroll
      for (int i = 0; i < 4; ++i)
#pragma unroll
        for (int j = 0; j < 4; ++j)
          acc[i][j] = fmaf(av[i], bv[j], acc[i][j]);
    }
    __syncthreads();
  }

#pragma unroll
  for (int i = 0; i < 4; ++i) {
    const int bb = brow + tr * 4 + i;
#pragma unroll
    for (int j = 0; j < 4; ++j) {
      const int hh = bcol + tc * 4 + j;
      cur1[(size_t)bb * NH_ + hh] = acc[i][j] + b1[hh];
    }
  }
}

// bf16 round-to-nearest-even of an f32, returned as the low 16 bits.
__device__ __forceinline__ unsigned int bf16_rne(float f) {
  unsigned int u = __float_as_uint(f);
  return (u + 0x7FFFu + ((u >> 16) & 1u)) >> 16;
}

// ---------------- Kernel 2: fused LIF loop, 8 batches/block, MFMA layer-2 ---
// Wave w owns batch (blockIdx.x*8 + w): 32 h-states per lane (h = lane*32+i).
// Per step: LIF -> pack spikes bf16 -> LDS A-tile (fragment-order layout)
//   -> each wave MFMAs its K=256 chunk (8 kb x {hi,lo}) -> LDS combine
//   -> threads 0..79 finish cur2 + mem2 LIF + record.
__global__ __launch_bounds__(512, 2) void snn_loop(
    const float* __restrict__ cur1, const float* __restrict__ w2,
    const float* __restrict__ b2, float* __restrict__ spk2_rec,
    float* __restrict__ mem2_rec) {
  extern __shared__ char smem[];
  const int tid = threadIdx.x;
  const int lane = tid & 63;
  const int w = tid >> 6;               // wave id = local batch id
  const int bbase = blockIdx.x * GB_;
  const int bb = bbase + w;             // this wave's batch row

  // ---- zero the A-tile once (rows m=8..15 stay zero forever) ----
  {
    u32x4 z = {0, 0, 0, 0};
    for (int q = tid; q < A_BYTES / 16; q += 512)
      *reinterpret_cast<u32x4*>(smem + q * 16) = z;
  }

  // ---- load per-lane LIF state: 32 contiguous h's ----
  float mem1[32], c1v[32], spk[32];
  {
    const float* base = cur1 + (size_t)bb * NH_ + lane * 32;
#pragma unroll
    for (int q = 0; q < 8; ++q) {
      const float4 v = *reinterpret_cast<const float4*>(base + q * 4);
      c1v[q * 4 + 0] = v.x; c1v[q * 4 + 1] = v.y;
      c1v[q * 4 + 2] = v.z; c1v[q * 4 + 3] = v.w;
    }
#pragma unroll
    for (int i = 0; i < 32; ++i) { mem1[i] = 0.0f; spk[i] = 0.0f; }
  }

  // ---- preload w2 B-fragments (hi/lo split) for this wave's K-chunk ----
  // kb = w*8 + kbl; lane: n = lane&15 (output o), k = kb*32 + (lane>>4)*8 + j
  u32x4 bhi[8], blo[8];
  {
    const int o = lane & 15;
    const int koff = (lane >> 4) * 8;
#pragma unroll
    for (int kbl = 0; kbl < 8; ++kbl) {
      const int kb = w * 8 + kbl;
      unsigned int hw[4], lw[4];
#pragma unroll
      for (int p = 0; p < 4; ++p) {
        unsigned int h0 = 0, h1 = 0, l0 = 0, l1 = 0;
        if (o < NO_) {
          const int k = kb * 32 + koff + p * 2;
          const float f0 = w2[(size_t)o * NH_ + k];
          const float f1 = w2[(size_t)o * NH_ + k + 1];
          h0 = bf16_rne(f0);
          h1 = bf16_rne(f1);
          l0 = bf16_rne(f0 - __uint_as_float(h0 << 16));
          l1 = bf16_rne(f1 - __uint_as_float(h1 << 16));
        }
        hw[p] = h0 | (h1 << 16);
        lw[p] = l0 | (l1 << 16);
      }
      bhi[kbl] = u32x4{hw[0], hw[1], hw[2], hw[3]};
      blo[kbl] = u32x4{lw[0], lw[1], lw[2], lw[3]};
    }
  }

  // ---- mem2 ownership: thread tid<80 owns (b = tid/10, o = tid%10) ----
  float mem2 = 0.0f, spk2 = 0.0f, b2v = 0.0f;
  const int cb = tid / NO_;
  const int co = tid - cb * NO_;
  int comb_idx = 0;
  float* srec = nullptr; float* mrec = nullptr;
  if (tid < GB_ * NO_) {
    b2v = b2[co];
    const int clane = co + 16 * (cb >> 2);
    comb_idx = clane * 4 + (cb & 3);
    srec = spk2_rec + (size_t)(bbase + cb) * NO_ + co;
    mrec = mem2_rec + (size_t)(bbase + cb) * NO_ + co;
  }
  const float* combf = reinterpret_cast<const float*>(smem + COMB_OFF);

  __syncthreads();

  for (int t = 0; t < T_; ++t) {
    // ---- phase A: LIF + pack spikes to bf16 pair-words, write A-tile ----
#pragma unroll
    for (int i = 0; i < 32; ++i) {
      float m = fmaf(0.95f, mem1[i], c1v[i]);
      m = m - spk[i];
      mem1[i] = m;
      spk[i] = (m > 1.0f) ? 1.0f : 0.0f;
    }
    {
      // instance kb = lane; spike i -> slot lane'=(w+16*(i>>3)), byte (i&7)*2
      char* abase = smem + lane * INST_STRIDE + w * 16;
#pragma unroll
      for (int q = 0; q < 4; ++q) {
        u32x4 W;
#pragma unroll
        for (int p = 0; p < 4; ++p) {
          const int i0 = q * 8 + p * 2;
          // bf16(spk) pair: spk is exactly 0.0f or 1.0f -> top16 of f32 bits
          W[p] = __builtin_amdgcn_perm(__float_as_uint(spk[i0 + 1]),
                                       __float_as_uint(spk[i0]), 0x07060302u);
        }
        *reinterpret_cast<u32x4*>(abase + q * 256) = W;
      }
    }
    __syncthreads();

    // ---- phase B: MFMA this wave's K-chunk over all 8 batches ----
    {
      f32x4 acc = {0.0f, 0.0f, 0.0f, 0.0f};
#pragma unroll
      for (int kbl = 0; kbl < 8; ++kbl) {
        const int kb = w * 8 + kbl;
        const short8 af = *reinterpret_cast<const short8*>(
            smem + kb * INST_STRIDE + lane * 16);
        acc = __builtin_amdgcn_mfma_f32_16x16x32_bf16(
            af, __builtin_bit_cast(short8, bhi[kbl]), acc, 0, 0, 0);
        acc = __builtin_amdgcn_mfma_f32_16x16x32_bf16(
            af, __builtin_bit_cast(short8, blo[kbl]), acc, 0, 0, 0);
      }
      *reinterpret_cast<f32x4*>(smem + COMB_OFF + w * 1024 + lane * 16) = acc;
    }
    __syncthreads();

    // ---- phase C: combine partials, mem2 LIF, record ----
    if (tid < GB_ * NO_) {
      const float s01 = combf[comb_idx] + combf[256 + comb_idx];
      const float s23 = combf[512 + comb_idx] + combf[768 + comb_idx];
      const float s45 = combf[1024 + comb_idx] + combf[1280 + comb_idx];
      const float s67 = combf[1536 + comb_idx] + combf[1792 + comb_idx];
      const float cur2 = ((s01 + s23) + (s45 + s67)) + b2v;
      float m = fmaf(0.95f, mem2, cur2);
      m = m - spk2;
      mem2 = m;
      spk2 = (m > 1.0f) ? 1.0f : 0.0f;
      srec[(size_t)t * (B_ * NO_)] = spk2;
      mrec[(size_t)t * (B_ * NO_)] = m;
    }
    __syncthreads();
  }
}

// ---------------------------------------------------------------------------
extern "C" void kernel_launch(void* const* d_in, const int* in_sizes, int n_in,
                              void* d_out, int out_size, void* d_ws, size_t ws_size,
                              hipStream_t stream) {
  const float* x  = (const float*)d_in[0];
  const float* w1 = (const float*)d_in[1];
  const float* b1 = (const float*)d_in[2];
  const float* w2 = (const float*)d_in[3];
  const float* b2 = (const float*)d_in[4];
  float* out = (float*)d_out;
  float* cur1 = (float*)d_ws;  // 16 MB scratch

  float* spk2_rec = out;
  float* mem2_rec = out + (size_t)T_ * B_ * NO_;

  (void)hipFuncSetAttribute(reinterpret_cast<const void*>(snn_loop),
                            hipFuncAttributeMaxDynamicSharedMemorySize,
                            SMEM_BYTES);

  dim3 g1(NH_ / 64, B_ / 64);
  gemm_cur1<<<g1, 256, 0, stream>>>(x, w1, b1, cur1);
  snn_loop<<<NBLK, 512, SMEM_BYTES, stream>>>(cur1, w2, b2, spk2_rec, mem2_rec);
}

// Round 8
// 262.205 us; speedup vs baseline: 2.0454x; 1.0660x over previous
//
#include <hip/hip_runtime.h>
#include <hip/hip_bf16.h>

// SNN: B=2048, NI=1024, NH=2048, NO=10, T=128, BETA=0.95, THR=1.0
// Layer-1 LIF is autonomous (no feedback from layer 2) -> generate spikes in
// T-chunks, then GEMM with TIME as the MFMA M-dimension (all 16 rows useful),
// spikes stored as bits in LDS, w2 (hi/lo bf16 split) in registers.

#define B_   2048
#define NI_  1024
#define NH_  2048
#define NO_  10
#define T_   128
#define GB_  8          // batches per block (1 per wave)
#define NBLK (B_ / GB_) // 256 blocks = 1 per CU
#define TC_  32         // timesteps per chunk
#define NCH  (T_ / TC_)

typedef __attribute__((ext_vector_type(8))) short short8;
typedef __attribute__((ext_vector_type(4))) float f32x4;
typedef __attribute__((ext_vector_type(4))) unsigned int u32x4;

// LDS map (bytes):
//   bits   u32[8 batch][TC_][65 pad-words]          = 66560   at 0
//   stag   f32[8 batch][TC_][10]  (ALIASES bits; bits dead after MFMA phase)
//   comb   f32[8 w][8 b][2 tb][4 g][10 n][4 r]      = 81920   at 66560
#define BITS_OFF 0
#define STAG_OFF 0
#define COMB_OFF 66560
#define SMEM_BYTES 148480

// ---------------- Kernel 1: cur1 = x @ w1^T + b1 (fp32, LDS-tiled) ----------
#define BK 32

__global__ __launch_bounds__(256) void gemm_cur1(
    const float* __restrict__ x, const float* __restrict__ w1,
    const float* __restrict__ b1, float* __restrict__ cur1) {
  __shared__ __align__(16) float At[BK][68];
  __shared__ __align__(16) float Bt[BK][68];
  const int tid = threadIdx.x;
  const int brow = blockIdx.y * 64;
  const int bcol = blockIdx.x * 64;
  const int tr = tid >> 4;
  const int tc = tid & 15;

  float acc[4][4] = {};

  for (int kt = 0; kt < NI_; kt += BK) {
#pragma unroll
    for (int p = 0; p < 2; ++p) {
      const int f = tid + p * 256;
      const int row = f >> 3;
      const int kq = f & 7;
      const float4 av = *reinterpret_cast<const float4*>(
          &x[(size_t)(brow + row) * NI_ + kt + kq * 4]);
      const float4 bv = *reinterpret_cast<const float4*>(
          &w1[(size_t)(bcol + row) * NI_ + kt + kq * 4]);
      At[kq * 4 + 0][row] = av.x; At[kq * 4 + 1][row] = av.y;
      At[kq * 4 + 2][row] = av.z; At[kq * 4 + 3][row] = av.w;
      Bt[kq * 4 + 0][row] = bv.x; Bt[kq * 4 + 1][row] = bv.y;
      Bt[kq * 4 + 2][row] = bv.z; Bt[kq * 4 + 3][row] = bv.w;
    }
    __syncthreads();
#pragma unroll 8
    for (int kk = 0; kk < BK; ++kk) {
      const float4 a4 = *reinterpret_cast<const float4*>(&At[kk][tr * 4]);
      const float4 b4 = *reinterpret_cast<const float4*>(&Bt[kk][tc * 4]);
      const float av[4] = {a4.x, a4.y, a4.z, a4.w};
      const float bv[4] = {b4.x, b4.y, b4.z, b4.w};
#pragma unroll
      for (int i = 0; i < 4; ++i)
#pragma unroll
        for (int j = 0; j < 4; ++j)
          acc[i][j] = fmaf(av[i], bv[j], acc[i][j]);
    }
    __syncthreads();
  }

#pragma unroll
  for (int i = 0; i < 4; ++i) {
    const int bb = brow + tr * 4 + i;
#pragma unroll
    for (int j = 0; j < 4; ++j) {
      const int hh = bcol + tc * 4 + j;
      cur1[(size_t)bb * NH_ + hh] = acc[i][j] + b1[hh];
    }
  }
}

// bf16 round-to-nearest-even of an f32, low 16 bits.
__device__ __forceinline__ unsigned int bf16_rne(float f) {
  unsigned int u = __float_as_uint(f);
  return (u + 0x7FFFu + ((u >> 16) & 1u)) >> 16;
}

// ---------------- Kernel 2: chunked LIF + time-as-M MFMA -------------------
__global__ __launch_bounds__(512, 2) void snn_loop(
    const float* __restrict__ cur1, const float* __restrict__ w2,
    const float* __restrict__ b2, float* __restrict__ spk2_rec,
    float* __restrict__ mem2_rec) {
  extern __shared__ char smem[];
  unsigned* bits = reinterpret_cast<unsigned*>(smem + BITS_OFF);
  float* comb = reinterpret_cast<float*>(smem + COMB_OFF);
  float* stag = reinterpret_cast<float*>(smem + STAG_OFF);
  const int tid = threadIdx.x;
  const int lane = tid & 63;
  const int w = tid >> 6;               // wave id = local batch id
  const int bbase = blockIdx.x * GB_;
  const int bb = bbase + w;

  // ---- layer-1 state: 32 contiguous h per lane (h = lane*32 + i) ----
  float mem1[32], c1v[32], spk[32];
  {
    const float* base = cur1 + (size_t)bb * NH_ + lane * 32;
#pragma unroll
    for (int q = 0; q < 8; ++q) {
      const float4 v = *reinterpret_cast<const float4*>(base + q * 4);
      c1v[q * 4 + 0] = v.x; c1v[q * 4 + 1] = v.y;
      c1v[q * 4 + 2] = v.z; c1v[q * 4 + 3] = v.w;
    }
#pragma unroll
    for (int i = 0; i < 32; ++i) { mem1[i] = 0.0f; spk[i] = 0.0f; }
  }

  // ---- w2 B-fragments in registers (hi/lo split) — round-4-verified ----
  // kb = w*8+kbl; lane: n = lane&15 (o), k = kb*32 + (lane>>4)*8 + j
  u32x4 bhi[8], blo[8];
  {
    const int o = lane & 15;
    const int koff = (lane >> 4) * 8;
#pragma unroll
    for (int kbl = 0; kbl < 8; ++kbl) {
      const int kb = w * 8 + kbl;
      unsigned int hw[4], lw[4];
#pragma unroll
      for (int p = 0; p < 4; ++p) {
        unsigned int h0 = 0, h1 = 0, l0 = 0, l1 = 0;
        if (o < NO_) {
          const int k = kb * 32 + koff + p * 2;
          const float f0 = w2[(size_t)o * NH_ + k];
          const float f1 = w2[(size_t)o * NH_ + k + 1];
          h0 = bf16_rne(f0);
          h1 = bf16_rne(f1);
          l0 = bf16_rne(f0 - __uint_as_float(h0 << 16));
          l1 = bf16_rne(f1 - __uint_as_float(h1 << 16));
        }
        hw[p] = h0 | (h1 << 16);
        lw[p] = l0 | (l1 << 16);
      }
      bhi[kbl] = u32x4{hw[0], hw[1], hw[2], hw[3]};
      blo[kbl] = u32x4{lw[0], lw[1], lw[2], lw[3]};
    }
  }

  // ---- layer-2 state: lane o<10 of wave w owns (batch bb, output o) ----
  float mem2 = 0.0f, spk2 = 0.0f, b2v = 0.0f;
  float *srec = nullptr, *mrec = nullptr;
  if (lane < NO_) {
    b2v = b2[lane];
    srec = spk2_rec + (size_t)bb * NO_ + lane;
    mrec = mem2_rec + (size_t)bb * NO_ + lane;
  }

  const int n15 = lane & 15;   // A row (t mod 16) AND D col (o)
  const int g = lane >> 4;     // A k-group AND D row-group

  for (int ch = 0; ch < NCH; ++ch) {
    // ---- phase 1: LIF for TC_ steps, pack spike bits to LDS ----
    for (int tl = 0; tl < TC_; ++tl) {
      unsigned W0 = 0, W1 = 0;
#pragma unroll
      for (int i = 0; i < 16; ++i) {
        float m = fmaf(0.95f, mem1[i], c1v[i]);
        m = m - spk[i];
        mem1[i] = m;
        const float s = (m > 1.0f) ? 1.0f : 0.0f;
        spk[i] = s;
        W0 |= ((__float_as_uint(s) >> 23) & 1u) << i;
      }
#pragma unroll
      for (int i = 16; i < 32; ++i) {
        float m = fmaf(0.95f, mem1[i], c1v[i]);
        m = m - spk[i];
        mem1[i] = m;
        const float s = (m > 1.0f) ? 1.0f : 0.0f;
        spk[i] = s;
        W1 |= ((__float_as_uint(s) >> 23) & 1u) << (i - 16);
      }
      bits[(w * TC_ + tl) * 65 + lane] = W0 | (W1 << 16);
    }
    __syncthreads();  // B1: bits(c) complete

    // ---- phase 2: MFMA partial cur2 over this wave's K-chunk ----
    {
      const unsigned char* bytes = reinterpret_cast<const unsigned char*>(smem);
      for (int b = 0; b < GB_; ++b) {
#pragma unroll
        for (int tb = 0; tb < 2; ++tb) {
          f32x4 acc = {0.0f, 0.0f, 0.0f, 0.0f};
#pragma unroll
          for (int kbl = 0; kbl < 8; ++kbl) {
            const int kb = w * 8 + kbl;
            const unsigned byt =
                bytes[((b * TC_ + tb * 16 + n15) * 65 + kb) * 4 + g];
            const unsigned wlo = ((byt & 0xFu) * 0x00204081u) & 0x01010101u;
            const unsigned whi = (((byt >> 4) & 0xFu) * 0x00204081u) & 0x01010101u;
            u32x4 A;
            A[0] = __builtin_amdgcn_perm(0u, wlo, 0x04010400u) * 0x3F80u;
            A[1] = __builtin_amdgcn_perm(0u, wlo, 0x04030402u) * 0x3F80u;
            A[2] = __builtin_amdgcn_perm(0u, whi, 0x04010400u) * 0x3F80u;
            A[3] = __builtin_amdgcn_perm(0u, whi, 0x04030402u) * 0x3F80u;
            const short8 af = __builtin_bit_cast(short8, A);
            acc = __builtin_amdgcn_mfma_f32_16x16x32_bf16(
                af, __builtin_bit_cast(short8, bhi[kbl]), acc, 0, 0, 0);
            acc = __builtin_amdgcn_mfma_f32_16x16x32_bf16(
                af, __builtin_bit_cast(short8, blo[kbl]), acc, 0, 0, 0);
          }
          if (n15 < NO_)
            *reinterpret_cast<f32x4*>(
                &comb[((((w * 8 + b) * 2 + tb) * 4 + g) * 40) + n15 * 4]) = acc;
        }
      }
    }
    __syncthreads();  // B2: comb(c) complete; bits(c) dead

    // ---- phase 3: sum 8 wave-partials -> staging (aliases bits) ----
#pragma unroll
    for (int j = 0; j < 5; ++j) {
      const int f = tid + j * 512;          // 0..2559
      const int b = f / 320;
      const int r320 = f - b * 320;
      const int tb = r320 / 160;
      const int r160 = r320 - tb * 160;
      const int g2 = r160 / 40;
      const int r40 = r160 - g2 * 40;
      const int n = r40 >> 2;
      const int r = r40 & 3;
      const int base = (((b * 2 + tb) * 4 + g2) * 40) + n * 4 + r;
      float s = 0.0f;
#pragma unroll
      for (int ww = 0; ww < 8; ++ww) s += comb[ww * 2560 + base];
      const int tl = tb * 16 + g2 * 4 + r;  // D: row = g*4 + reg
      stag[(b * TC_ + tl) * 10 + n] = s;
    }
    __syncthreads();  // B3: staging complete

    // ---- phase 4: mem2 scan (10 lanes per wave, own batch) ----
    if (lane < NO_) {
      for (int tl = 0; tl < TC_; ++tl) {
        const float cur2 = stag[(w * TC_ + tl) * 10 + lane] + b2v;
        float m = fmaf(0.95f, mem2, cur2);
        m = m - spk2;
        mem2 = m;
        spk2 = (m > 1.0f) ? 1.0f : 0.0f;
        const int t = ch * TC_ + tl;
        srec[(size_t)t * (B_ * NO_)] = spk2;
        mrec[(size_t)t * (B_ * NO_)] = m;
      }
    }
    __syncthreads();  // B4: staging consumed before next chunk's bits
  }
}

// ---------------------------------------------------------------------------
extern "C" void kernel_launch(void* const* d_in, const int* in_sizes, int n_in,
                              void* d_out, int out_size, void* d_ws, size_t ws_size,
                              hipStream_t stream) {
  const float* x  = (const float*)d_in[0];
  const float* w1 = (const float*)d_in[1];
  const float* b1 = (const float*)d_in[2];
  const float* w2 = (const float*)d_in[3];
  const float* b2 = (const float*)d_in[4];
  float* out = (float*)d_out;
  float* cur1 = (float*)d_ws;  // 16 MB scratch

  float* spk2_rec = out;
  float* mem2_rec = out + (size_t)T_ * B_ * NO_;

  (void)hipFuncSetAttribute(reinterpret_cast<const void*>(snn_loop),
                            hipFuncAttributeMaxDynamicSharedMemorySize,
                            SMEM_BYTES);

  dim3 g1(NH_ / 64, B_ / 64);
  gemm_cur1<<<g1, 256, 0, stream>>>(x, w1, b1, cur1);
  snn_loop<<<NBLK, 512, SMEM_BYTES, stream>>>(cur1, w2, b2, spk2_rec, mem2_rec);
}

// Round 9
// 202.440 us; speedup vs baseline: 2.6492x; 1.2952x over previous
//
#include <hip/hip_runtime.h>
#include <hip/hip_bf16.h>

// SNN: B=2048, NI=1024, NH=2048, NO=10, T=128, BETA=0.95, THR=1.0
// K1: cur1 = x @ w1^T + b1 via bf16x3 MFMA (hi/lo split, hh+hl+lh terms).
// K2: chunked LIF + time-as-M MFMA (round-6 verified, unchanged).

#define B_   2048
#define NI_  1024
#define NH_  2048
#define NO_  10
#define T_   128
#define GB_  8
#define NBLK (B_ / GB_)
#define TC_  32
#define NCH  (T_ / TC_)

typedef __attribute__((ext_vector_type(8))) short short8;
typedef __attribute__((ext_vector_type(4))) float f32x4;
typedef __attribute__((ext_vector_type(4))) unsigned int u32x4;

// bf16 round-to-nearest-even of an f32, low 16 bits.
__device__ __forceinline__ unsigned int bf16_rne(float f) {
  unsigned int u = __float_as_uint(f);
  return (u + 0x7FFFu + ((u >> 16) & 1u)) >> 16;
}

// ---------------- Kernel 1: cur1 = x @ w1^T + b1 (bf16x3 MFMA) --------------
// 128x128 tile, K-step 32, 512 threads (8 waves: wm = wv>>2, wn = wv&3).
// LDS row layout (stride 144 B): [hi 32 bf16 | lo 32 bf16 | 16 B pad].
#define G_ASTRIDE 144
#define G_AOFF    0
#define G_BOFF    (128 * G_ASTRIDE)   // 18432
#define G_SMEM    (2 * 128 * G_ASTRIDE)

__global__ __launch_bounds__(512, 4) void gemm_cur1(
    const float* __restrict__ x, const float* __restrict__ w1,
    const float* __restrict__ b1, float* __restrict__ cur1) {
  __shared__ __align__(16) char smem[G_SMEM];
  const int tid = threadIdx.x;
  const int lane = tid & 63;
  const int wv = tid >> 6;
  const int wm = wv >> 2;        // 0..1: M half (64 rows)
  const int wn = wv & 3;         // 0..3: N quarter (32 cols)
  const int n15 = lane & 15;
  const int g = lane >> 4;
  const int brow = blockIdx.y * 128;
  const int bcol = blockIdx.x * 128;

  const int r_st = tid >> 3;     // staging row 0..63 (+64 for p=1)
  const int kq = tid & 7;        // float4 slot within the 32-wide K tile

  f32x4 acc[4][2];
#pragma unroll
  for (int tm = 0; tm < 4; ++tm)
#pragma unroll
    for (int tn = 0; tn < 2; ++tn) acc[tm][tn] = f32x4{0, 0, 0, 0};

  for (int kt = 0; kt < NI_; kt += 32) {
    // ---- stage + convert hi/lo: each thread 2 rows of x and 2 of w1 ----
#pragma unroll
    for (int p = 0; p < 2; ++p) {
      const int r = r_st + p * 64;
      const float4 va = *reinterpret_cast<const float4*>(
          &x[(size_t)(brow + r) * NI_ + kt + kq * 4]);
      const float4 vb = *reinterpret_cast<const float4*>(
          &w1[(size_t)(bcol + r) * NI_ + kt + kq * 4]);
      const float fa[4] = {va.x, va.y, va.z, va.w};
      const float fb[4] = {vb.x, vb.y, vb.z, vb.w};
      unsigned ha[4], la[4], hb[4], lb[4];
#pragma unroll
      for (int c = 0; c < 4; ++c) {
        ha[c] = bf16_rne(fa[c]);
        la[c] = bf16_rne(fa[c] - __uint_as_float(ha[c] << 16));
        hb[c] = bf16_rne(fb[c]);
        lb[c] = bf16_rne(fb[c] - __uint_as_float(hb[c] << 16));
      }
      char* arow = smem + G_AOFF + r * G_ASTRIDE;
      char* brw  = smem + G_BOFF + r * G_ASTRIDE;
      *reinterpret_cast<uint2*>(arow + kq * 8) =
          uint2{ha[0] | (ha[1] << 16), ha[2] | (ha[3] << 16)};
      *reinterpret_cast<uint2*>(arow + 64 + kq * 8) =
          uint2{la[0] | (la[1] << 16), la[2] | (la[3] << 16)};
      *reinterpret_cast<uint2*>(brw + kq * 8) =
          uint2{hb[0] | (hb[1] << 16), hb[2] | (hb[3] << 16)};
      *reinterpret_cast<uint2*>(brw + 64 + kq * 8) =
          uint2{lb[0] | (lb[1] << 16), lb[2] | (lb[3] << 16)};
    }
    __syncthreads();

    // ---- fragments + 24 MFMA ----
    short8 ah[4], al[4], bh2[2], bl2[2];
#pragma unroll
    for (int tm = 0; tm < 4; ++tm) {
      const char* p = smem + G_AOFF + (wm * 64 + tm * 16 + n15) * G_ASTRIDE;
      ah[tm] = *reinterpret_cast<const short8*>(p + g * 16);
      al[tm] = *reinterpret_cast<const short8*>(p + 64 + g * 16);
    }
#pragma unroll
    for (int tn = 0; tn < 2; ++tn) {
      const char* p = smem + G_BOFF + (wn * 32 + tn * 16 + n15) * G_ASTRIDE;
      bh2[tn] = *reinterpret_cast<const short8*>(p + g * 16);
      bl2[tn] = *reinterpret_cast<const short8*>(p + 64 + g * 16);
    }
#pragma unroll
    for (int tm = 0; tm < 4; ++tm)
#pragma unroll
      for (int tn = 0; tn < 2; ++tn) {
        acc[tm][tn] = __builtin_amdgcn_mfma_f32_16x16x32_bf16(
            ah[tm], bh2[tn], acc[tm][tn], 0, 0, 0);
        acc[tm][tn] = __builtin_amdgcn_mfma_f32_16x16x32_bf16(
            ah[tm], bl2[tn], acc[tm][tn], 0, 0, 0);
        acc[tm][tn] = __builtin_amdgcn_mfma_f32_16x16x32_bf16(
            al[tm], bh2[tn], acc[tm][tn], 0, 0, 0);
      }
    __syncthreads();
  }

  // ---- epilogue: D map (verified): col = lane&15, row = (lane>>4)*4+reg ----
#pragma unroll
  for (int tn = 0; tn < 2; ++tn) {
    const int col = bcol + wn * 32 + tn * 16 + n15;
    const float bias = b1[col];
#pragma unroll
    for (int tm = 0; tm < 4; ++tm) {
      const int rowb = brow + wm * 64 + tm * 16 + g * 4;
#pragma unroll
      for (int r = 0; r < 4; ++r)
        cur1[(size_t)(rowb + r) * NH_ + col] = acc[tm][tn][r] + bias;
    }
  }
}

// ---------------- Kernel 2: chunked LIF + time-as-M MFMA (unchanged) -------
#define BITS_OFF 0
#define STAG_OFF 0
#define COMB_OFF 66560
#define SMEM_BYTES 148480

__global__ __launch_bounds__(512, 2) void snn_loop(
    const float* __restrict__ cur1, const float* __restrict__ w2,
    const float* __restrict__ b2, float* __restrict__ spk2_rec,
    float* __restrict__ mem2_rec) {
  extern __shared__ char smem[];
  unsigned* bits = reinterpret_cast<unsigned*>(smem + BITS_OFF);
  float* comb = reinterpret_cast<float*>(smem + COMB_OFF);
  float* stag = reinterpret_cast<float*>(smem + STAG_OFF);
  const int tid = threadIdx.x;
  const int lane = tid & 63;
  const int w = tid >> 6;
  const int bbase = blockIdx.x * GB_;
  const int bb = bbase + w;

  float mem1[32], c1v[32], spk[32];
  {
    const float* base = cur1 + (size_t)bb * NH_ + lane * 32;
#pragma unroll
    for (int q = 0; q < 8; ++q) {
      const float4 v = *reinterpret_cast<const float4*>(base + q * 4);
      c1v[q * 4 + 0] = v.x; c1v[q * 4 + 1] = v.y;
      c1v[q * 4 + 2] = v.z; c1v[q * 4 + 3] = v.w;
    }
#pragma unroll
    for (int i = 0; i < 32; ++i) { mem1[i] = 0.0f; spk[i] = 0.0f; }
  }

  u32x4 bhi[8], blo[8];
  {
    const int o = lane & 15;
    const int koff = (lane >> 4) * 8;
#pragma unroll
    for (int kbl = 0; kbl < 8; ++kbl) {
      const int kb = w * 8 + kbl;
      unsigned int hw[4], lw[4];
#pragma unroll
      for (int p = 0; p < 4; ++p) {
        unsigned int h0 = 0, h1 = 0, l0 = 0, l1 = 0;
        if (o < NO_) {
          const int k = kb * 32 + koff + p * 2;
          const float f0 = w2[(size_t)o * NH_ + k];
          const float f1 = w2[(size_t)o * NH_ + k + 1];
          h0 = bf16_rne(f0);
          h1 = bf16_rne(f1);
          l0 = bf16_rne(f0 - __uint_as_float(h0 << 16));
          l1 = bf16_rne(f1 - __uint_as_float(h1 << 16));
        }
        hw[p] = h0 | (h1 << 16);
        lw[p] = l0 | (l1 << 16);
      }
      bhi[kbl] = u32x4{hw[0], hw[1], hw[2], hw[3]};
      blo[kbl] = u32x4{lw[0], lw[1], lw[2], lw[3]};
    }
  }

  float mem2 = 0.0f, spk2 = 0.0f, b2v = 0.0f;
  float *srec = nullptr, *mrec = nullptr;
  if (lane < NO_) {
    b2v = b2[lane];
    srec = spk2_rec + (size_t)bb * NO_ + lane;
    mrec = mem2_rec + (size_t)bb * NO_ + lane;
  }

  const int n15 = lane & 15;
  const int g = lane >> 4;

  for (int ch = 0; ch < NCH; ++ch) {
    for (int tl = 0; tl < TC_; ++tl) {
      unsigned W0 = 0, W1 = 0;
#pragma unroll
      for (int i = 0; i < 16; ++i) {
        float m = fmaf(0.95f, mem1[i], c1v[i]);
        m = m - spk[i];
        mem1[i] = m;
        const float s = (m > 1.0f) ? 1.0f : 0.0f;
        spk[i] = s;
        W0 |= ((__float_as_uint(s) >> 23) & 1u) << i;
      }
#pragma unroll
      for (int i = 16; i < 32; ++i) {
        float m = fmaf(0.95f, mem1[i], c1v[i]);
        m = m - spk[i];
        mem1[i] = m;
        const float s = (m > 1.0f) ? 1.0f : 0.0f;
        spk[i] = s;
        W1 |= ((__float_as_uint(s) >> 23) & 1u) << (i - 16);
      }
      bits[(w * TC_ + tl) * 65 + lane] = W0 | (W1 << 16);
    }
    __syncthreads();  // B1

    {
      const unsigned char* bytes = reinterpret_cast<const unsigned char*>(smem);
      for (int b = 0; b < GB_; ++b) {
#pragma unroll
        for (int tb = 0; tb < 2; ++tb) {
          f32x4 acc = {0.0f, 0.0f, 0.0f, 0.0f};
#pragma unroll
          for (int kbl = 0; kbl < 8; ++kbl) {
            const int kb = w * 8 + kbl;
            const unsigned byt =
                bytes[((b * TC_ + tb * 16 + n15) * 65 + kb) * 4 + g];
            const unsigned wlo = ((byt & 0xFu) * 0x00204081u) & 0x01010101u;
            const unsigned whi = (((byt >> 4) & 0xFu) * 0x00204081u) & 0x01010101u;
            u32x4 A;
            A[0] = __builtin_amdgcn_perm(0u, wlo, 0x04010400u) * 0x3F80u;
            A[1] = __builtin_amdgcn_perm(0u, wlo, 0x04030402u) * 0x3F80u;
            A[2] = __builtin_amdgcn_perm(0u, whi, 0x04010400u) * 0x3F80u;
            A[3] = __builtin_amdgcn_perm(0u, whi, 0x04030402u) * 0x3F80u;
            const short8 af = __builtin_bit_cast(short8, A);
            acc = __builtin_amdgcn_mfma_f32_16x16x32_bf16(
                af, __builtin_bit_cast(short8, bhi[kbl]), acc, 0, 0, 0);
            acc = __builtin_amdgcn_mfma_f32_16x16x32_bf16(
                af, __builtin_bit_cast(short8, blo[kbl]), acc, 0, 0, 0);
          }
          if (n15 < NO_)
            *reinterpret_cast<f32x4*>(
                &comb[((((w * 8 + b) * 2 + tb) * 4 + g) * 40) + n15 * 4]) = acc;
        }
      }
    }
    __syncthreads();  // B2

#pragma unroll
    for (int j = 0; j < 5; ++j) {
      const int f = tid + j * 512;
      const int b = f / 320;
      const int r320 = f - b * 320;
      const int tb = r320 / 160;
      const int r160 = r320 - tb * 160;
      const int g2 = r160 / 40;
      const int r40 = r160 - g2 * 40;
      const int n = r40 >> 2;
      const int r = r40 & 3;
      const int base = (((b * 2 + tb) * 4 + g2) * 40) + n * 4 + r;
      float s = 0.0f;
#pragma unroll
      for (int ww = 0; ww < 8; ++ww) s += comb[ww * 2560 + base];
      const int tl = tb * 16 + g2 * 4 + r;
      stag[(b * TC_ + tl) * 10 + n] = s;
    }
    __syncthreads();  // B3

    if (lane < NO_) {
      for (int tl = 0; tl < TC_; ++tl) {
        const float cur2 = stag[(w * TC_ + tl) * 10 + lane] + b2v;
        float m = fmaf(0.95f, mem2, cur2);
        m = m - spk2;
        mem2 = m;
        spk2 = (m > 1.0f) ? 1.0f : 0.0f;
        const int t = ch * TC_ + tl;
        srec[(size_t)t * (B_ * NO_)] = spk2;
        mrec[(size_t)t * (B_ * NO_)] = m;
      }
    }
    __syncthreads();  // B4
  }
}

// ---------------------------------------------------------------------------
extern "C" void kernel_launch(void* const* d_in, const int* in_sizes, int n_in,
                              void* d_out, int out_size, void* d_ws, size_t ws_size,
                              hipStream_t stream) {
  const float* x  = (const float*)d_in[0];
  const float* w1 = (const float*)d_in[1];
  const float* b1 = (const float*)d_in[2];
  const float* w2 = (const float*)d_in[3];
  const float* b2 = (const float*)d_in[4];
  float* out = (float*)d_out;
  float* cur1 = (float*)d_ws;

  float* spk2_rec = out;
  float* mem2_rec = out + (size_t)T_ * B_ * NO_;

  (void)hipFuncSetAttribute(reinterpret_cast<const void*>(snn_loop),
                            hipFuncAttributeMaxDynamicSharedMemorySize,
                            SMEM_BYTES);

  dim3 g1(NH_ / 128, B_ / 128);
  gemm_cur1<<<g1, 512, 0, stream>>>(x, w1, b1, cur1);
  snn_loop<<<NBLK, 512, SMEM_BYTES, stream>>>(cur1, w2, b2, spk2_rec, mem2_rec);
}

// Round 10
// 191.566 us; speedup vs baseline: 2.7996x; 1.0568x over previous
//
#include <hip/hip_runtime.h>
#include <hip/hip_bf16.h>

// SNN: B=2048, NI=1024, NH=2048, NO=10, T=128, BETA=0.95, THR=1.0
// K1: cur1 = x @ w1^T + b1 via bf16x3 MFMA (round-8 verified, frozen).
// K2: chunked LIF + time-as-M MFMA; r10: LUT unpack, addc bit-collect,
//     wave-local phase-3, 2 barriers/chunk.

#define B_   2048
#define NI_  1024
#define NH_  2048
#define NO_  10
#define T_   128
#define GB_  8
#define NBLK (B_ / GB_)
#define TC_  32
#define NCH  (T_ / TC_)

typedef __attribute__((ext_vector_type(8))) short short8;
typedef __attribute__((ext_vector_type(4))) float f32x4;
typedef __attribute__((ext_vector_type(4))) unsigned int u32x4;

// bf16 round-to-nearest-even of an f32, low 16 bits.
__device__ __forceinline__ unsigned int bf16_rne(float f) {
  unsigned int u = __float_as_uint(f);
  return (u + 0x7FFFu + ((u >> 16) & 1u)) >> 16;
}

// ---------------- Kernel 1: cur1 = x @ w1^T + b1 (bf16x3 MFMA) --------------
#define G_ASTRIDE 144
#define G_AOFF    0
#define G_BOFF    (128 * G_ASTRIDE)
#define G_SMEM    (2 * 128 * G_ASTRIDE)

__global__ __launch_bounds__(512, 4) void gemm_cur1(
    const float* __restrict__ x, const float* __restrict__ w1,
    const float* __restrict__ b1, float* __restrict__ cur1) {
  __shared__ __align__(16) char smem[G_SMEM];
  const int tid = threadIdx.x;
  const int lane = tid & 63;
  const int wv = tid >> 6;
  const int wm = wv >> 2;
  const int wn = wv & 3;
  const int n15 = lane & 15;
  const int g = lane >> 4;
  const int brow = blockIdx.y * 128;
  const int bcol = blockIdx.x * 128;

  const int r_st = tid >> 3;
  const int kq = tid & 7;

  f32x4 acc[4][2];
#pragma unroll
  for (int tm = 0; tm < 4; ++tm)
#pragma unroll
    for (int tn = 0; tn < 2; ++tn) acc[tm][tn] = f32x4{0, 0, 0, 0};

  for (int kt = 0; kt < NI_; kt += 32) {
#pragma unroll
    for (int p = 0; p < 2; ++p) {
      const int r = r_st + p * 64;
      const float4 va = *reinterpret_cast<const float4*>(
          &x[(size_t)(brow + r) * NI_ + kt + kq * 4]);
      const float4 vb = *reinterpret_cast<const float4*>(
          &w1[(size_t)(bcol + r) * NI_ + kt + kq * 4]);
      const float fa[4] = {va.x, va.y, va.z, va.w};
      const float fb[4] = {vb.x, vb.y, vb.z, vb.w};
      unsigned ha[4], la[4], hb[4], lb[4];
#pragma unroll
      for (int c = 0; c < 4; ++c) {
        ha[c] = bf16_rne(fa[c]);
        la[c] = bf16_rne(fa[c] - __uint_as_float(ha[c] << 16));
        hb[c] = bf16_rne(fb[c]);
        lb[c] = bf16_rne(fb[c] - __uint_as_float(hb[c] << 16));
      }
      char* arow = smem + G_AOFF + r * G_ASTRIDE;
      char* brw  = smem + G_BOFF + r * G_ASTRIDE;
      *reinterpret_cast<uint2*>(arow + kq * 8) =
          uint2{ha[0] | (ha[1] << 16), ha[2] | (ha[3] << 16)};
      *reinterpret_cast<uint2*>(arow + 64 + kq * 8) =
          uint2{la[0] | (la[1] << 16), la[2] | (la[3] << 16)};
      *reinterpret_cast<uint2*>(brw + kq * 8) =
          uint2{hb[0] | (hb[1] << 16), hb[2] | (hb[3] << 16)};
      *reinterpret_cast<uint2*>(brw + 64 + kq * 8) =
          uint2{lb[0] | (lb[1] << 16), lb[2] | (lb[3] << 16)};
    }
    __syncthreads();

    short8 ah[4], al[4], bh2[2], bl2[2];
#pragma unroll
    for (int tm = 0; tm < 4; ++tm) {
      const char* p = smem + G_AOFF + (wm * 64 + tm * 16 + n15) * G_ASTRIDE;
      ah[tm] = *reinterpret_cast<const short8*>(p + g * 16);
      al[tm] = *reinterpret_cast<const short8*>(p + 64 + g * 16);
    }
#pragma unroll
    for (int tn = 0; tn < 2; ++tn) {
      const char* p = smem + G_BOFF + (wn * 32 + tn * 16 + n15) * G_ASTRIDE;
      bh2[tn] = *reinterpret_cast<const short8*>(p + g * 16);
      bl2[tn] = *reinterpret_cast<const short8*>(p + 64 + g * 16);
    }
#pragma unroll
    for (int tm = 0; tm < 4; ++tm)
#pragma unroll
      for (int tn = 0; tn < 2; ++tn) {
        acc[tm][tn] = __builtin_amdgcn_mfma_f32_16x16x32_bf16(
            ah[tm], bh2[tn], acc[tm][tn], 0, 0, 0);
        acc[tm][tn] = __builtin_amdgcn_mfma_f32_16x16x32_bf16(
            ah[tm], bl2[tn], acc[tm][tn], 0, 0, 0);
        acc[tm][tn] = __builtin_amdgcn_mfma_f32_16x16x32_bf16(
            al[tm], bh2[tn], acc[tm][tn], 0, 0, 0);
      }
    __syncthreads();
  }

#pragma unroll
  for (int tn = 0; tn < 2; ++tn) {
    const int col = bcol + wn * 32 + tn * 16 + n15;
    const float bias = b1[col];
#pragma unroll
    for (int tm = 0; tm < 4; ++tm) {
      const int rowb = brow + wm * 64 + tm * 16 + g * 4;
#pragma unroll
      for (int r = 0; r < 4; ++r)
        cur1[(size_t)(rowb + r) * NH_ + col] = acc[tm][tn][r] + bias;
    }
  }
}

// ---------------- Kernel 2: chunked LIF + time-as-M MFMA --------------------
// LDS map (bytes):
//   bits u32[8 b][32 tl][65]   at 0       (66560)
//   lut  uint2[16]             at 66560   (128)
//   comb f32[8 w][8 b][2][4][10][4] at 66688 (81920)
//   stag f32[8 b][32 tl][10]   at 148608  (10240)
#define BITS_OFF 0
#define LUT_OFF  66560
#define COMB_OFF 66688
#define STAG_OFF 148608
#define SMEM_BYTES 158848

__global__ __launch_bounds__(512, 2) void snn_loop(
    const float* __restrict__ cur1, const float* __restrict__ w2,
    const float* __restrict__ b2, float* __restrict__ spk2_rec,
    float* __restrict__ mem2_rec) {
  extern __shared__ char smem[];
  unsigned* bits = reinterpret_cast<unsigned*>(smem + BITS_OFF);
  uint2* lutw = reinterpret_cast<uint2*>(smem + LUT_OFF);
  const uint2* lut = lutw;
  float* comb = reinterpret_cast<float*>(smem + COMB_OFF);
  float* stag = reinterpret_cast<float*>(smem + STAG_OFF);
  const int tid = threadIdx.x;
  const int lane = tid & 63;
  const int w = tid >> 6;
  const int bbase = blockIdx.x * GB_;
  const int bb = bbase + w;

  // LUT: nibble -> two packed-bf16 words (bit j -> element j: 0 or 1.0bf16)
  if (tid < 16) {
    lutw[tid] = uint2{(tid & 1 ? 0x3F80u : 0u) | (tid & 2 ? 0x3F800000u : 0u),
                      (tid & 4 ? 0x3F80u : 0u) | (tid & 8 ? 0x3F800000u : 0u)};
  }

  // ---- layer-1 state: 32 contiguous h per lane (h = lane*32 + i) ----
  float mem1[32], c1v[32], spk[32];
  {
    const float* base = cur1 + (size_t)bb * NH_ + lane * 32;
#pragma unroll
    for (int q = 0; q < 8; ++q) {
      const float4 v = *reinterpret_cast<const float4*>(base + q * 4);
      c1v[q * 4 + 0] = v.x; c1v[q * 4 + 1] = v.y;
      c1v[q * 4 + 2] = v.z; c1v[q * 4 + 3] = v.w;
    }
#pragma unroll
    for (int i = 0; i < 32; ++i) { mem1[i] = 0.0f; spk[i] = 0.0f; }
  }

  // ---- w2 B-fragments in registers (hi/lo split) — verified ----
  u32x4 bhi[8], blo[8];
  {
    const int o = lane & 15;
    const int koff = (lane >> 4) * 8;
#pragma unroll
    for (int kbl = 0; kbl < 8; ++kbl) {
      const int kb = w * 8 + kbl;
      unsigned int hw[4], lw[4];
#pragma unroll
      for (int p = 0; p < 4; ++p) {
        unsigned int h0 = 0, h1 = 0, l0 = 0, l1 = 0;
        if (o < NO_) {
          const int k = kb * 32 + koff + p * 2;
          const float f0 = w2[(size_t)o * NH_ + k];
          const float f1 = w2[(size_t)o * NH_ + k + 1];
          h0 = bf16_rne(f0);
          h1 = bf16_rne(f1);
          l0 = bf16_rne(f0 - __uint_as_float(h0 << 16));
          l1 = bf16_rne(f1 - __uint_as_float(h1 << 16));
        }
        hw[p] = h0 | (h1 << 16);
        lw[p] = l0 | (l1 << 16);
      }
      bhi[kbl] = u32x4{hw[0], hw[1], hw[2], hw[3]};
      blo[kbl] = u32x4{lw[0], lw[1], lw[2], lw[3]};
    }
  }

  // ---- layer-2 state ----
  float mem2 = 0.0f, spk2 = 0.0f, b2v = 0.0f;
  float *srec = nullptr, *mrec = nullptr;
  if (lane < NO_) {
    b2v = b2[lane];
    srec = spk2_rec + (size_t)bb * NO_ + lane;
    mrec = mem2_rec + (size_t)bb * NO_ + lane;
  }

  const int n15 = lane & 15;
  const int g = lane >> 4;

  // ---- phase-3' per-lane offsets (5 comb words -> 5 stag words) ----
  int rd_off[5], wr_off[5];
#pragma unroll
  for (int j = 0; j < 5; ++j) {
    const int q = lane * 5 + j;          // 0..319 within this wave's batch
    const int tb = q / 160;
    const int r160 = q - tb * 160;
    const int g2 = r160 / 40;
    const int r40 = r160 - g2 * 40;
    const int n = r40 >> 2;
    const int r = r40 & 3;
    rd_off[j] = w * 320 + q;             // + ww*2560 in the loop
    wr_off[j] = (w * TC_ + tb * 16 + g2 * 4 + r) * 10 + n;
  }

  unsigned* bitsw = bits + w * (TC_ * 65) + lane;
  const unsigned char* bytes = reinterpret_cast<const unsigned char*>(smem);

  for (int ch = 0; ch < NCH; ++ch) {
    // ---- phase 1: LIF for TC_ steps; descending-i addc bit collect ----
    for (int tl = 0; tl < TC_; ++tl) {
      unsigned W = 0;
#pragma unroll
      for (int i = 31; i >= 0; --i) {
        float m = fmaf(0.95f, mem1[i], c1v[i]);
        m = m - spk[i];
        mem1[i] = m;
        const bool c = m > 1.0f;
        W = W + W + (c ? 1u : 0u);       // v_cmp + v_addc
        spk[i] = c ? 1.0f : 0.0f;        // cndmask off same vcc
      }
      bitsw[tl * 65] = W;
    }
    __syncthreads();  // B1: bits ready (also fences comb vs prev P3')

    // ---- phase 2: MFMA partials over this wave's K-chunk, all batches ----
    for (int b = 0; b < GB_; ++b) {
#pragma unroll
      for (int tb = 0; tb < 2; ++tb) {
        f32x4 acc = {0.0f, 0.0f, 0.0f, 0.0f};
#pragma unroll
        for (int kbl = 0; kbl < 8; ++kbl) {
          const int kb = w * 8 + kbl;
          const unsigned byt =
              bytes[(b * 2080 + tb * 1040 + n15 * 65 + kb) * 4 + g];
          const uint2 lo2 = lut[byt & 15u];
          const uint2 hi2 = lut[byt >> 4];
          const u32x4 A = {lo2.x, lo2.y, hi2.x, hi2.y};
          const short8 af = __builtin_bit_cast(short8, A);
          acc = __builtin_amdgcn_mfma_f32_16x16x32_bf16(
              af, __builtin_bit_cast(short8, bhi[kbl]), acc, 0, 0, 0);
          acc = __builtin_amdgcn_mfma_f32_16x16x32_bf16(
              af, __builtin_bit_cast(short8, blo[kbl]), acc, 0, 0, 0);
        }
        if (n15 < NO_)
          *reinterpret_cast<f32x4*>(
              &comb[w * 2560 + b * 320 + tb * 160 + g * 40 + n15 * 4]) = acc;
      }
    }
    __syncthreads();  // B2: comb ready; bits dead

    // ---- phase 3': wave-local partial sum for OWN batch -> stag ----
#pragma unroll
    for (int j = 0; j < 5; ++j) {
      float s = 0.0f;
#pragma unroll
      for (int ww = 0; ww < 8; ++ww) s += comb[ww * 2560 + rd_off[j]];
      stag[wr_off[j]] = s;
    }
    // no barrier: stag slice [w] written and read only by wave w (lgkmcnt)

    // ---- phase 4: mem2 scan (wave-local) ----
    if (lane < NO_) {
      for (int tl = 0; tl < TC_; ++tl) {
        const float cur2 = stag[(w * TC_ + tl) * 10 + lane] + b2v;
        float m = fmaf(0.95f, mem2, cur2);
        m = m - spk2;
        mem2 = m;
        spk2 = (m > 1.0f) ? 1.0f : 0.0f;
        const int t = ch * TC_ + tl;
        srec[(size_t)t * (B_ * NO_)] = spk2;
        mrec[(size_t)t * (B_ * NO_)] = m;
      }
    }
    // no barrier: next P1 writes bits (dead since B2); comb overwrite is
    // fenced by the next B1.
  }
}

// ---------------------------------------------------------------------------
extern "C" void kernel_launch(void* const* d_in, const int* in_sizes, int n_in,
                              void* d_out, int out_size, void* d_ws, size_t ws_size,
                              hipStream_t stream) {
  const float* x  = (const float*)d_in[0];
  const float* w1 = (const float*)d_in[1];
  const float* b1 = (const float*)d_in[2];
  const float* w2 = (const float*)d_in[3];
  const float* b2 = (const float*)d_in[4];
  float* out = (float*)d_out;
  float* cur1 = (float*)d_ws;

  float* spk2_rec = out;
  float* mem2_rec = out + (size_t)T_ * B_ * NO_;

  (void)hipFuncSetAttribute(reinterpret_cast<const void*>(snn_loop),
                            hipFuncAttributeMaxDynamicSharedMemorySize,
                            SMEM_BYTES);

  dim3 g1(NH_ / 128, B_ / 128);
  gemm_cur1<<<g1, 512, 0, stream>>>(x, w1, b1, cur1);
  snn_loop<<<NBLK, 512, SMEM_BYTES, stream>>>(cur1, w2, b2, spk2_rec, mem2_rec);
}